// Round 2
// baseline (345.083 us; speedup 1.0000x reference)
//
#include <hip/hip_runtime.h>
#include <hip/hip_bf16.h>

// FrameWiseCrossAttention: kv_len==1 => softmax==1 => out = broadcast(v) @ Wo.T + bo
// where v = c @ Wv.T + bv. x/Wq/Wk are mathematically unused.
//
// B=2, T=16, tpf=1560, N=24960, DIM=1024. M = B*T = 32 rows.

#define DIM   1024
#define K4    (DIM / 4)     // 256 float4 per row
#define MROWS 32            // B*T
#define TPF   1560
#define CHUNK 26
#define SPLITS 60           // 60 * 26 = 1560

typedef float fvec4 __attribute__((ext_vector_type(4)));   // clang-native, OK for nontemporal builtins

// C[32,1024] = A[32,1024] @ W[1024,1024]^T + bias
// grid = 256 blocks, block = 256 threads (4 waves). Wave w of block b computes
// output column j = b*4 + w for all 32 rows.
__global__ __launch_bounds__(256) void gemm32(const float* __restrict__ A,
                                              const float* __restrict__ W,
                                              const float* __restrict__ bias,
                                              float* __restrict__ C) {
    // K-tile of A: 32 rows x 64 float4 (256 k-values) = 32 KB LDS
    __shared__ fvec4 aS[MROWS * 64];

    const int tid  = threadIdx.x;
    const int wave = tid >> 6;
    const int lane = tid & 63;
    const int j    = blockIdx.x * 4 + wave;   // output column

    const fvec4* __restrict__ A4   = (const fvec4*)A;
    const fvec4* __restrict__ Wrow = (const fvec4*)(W + (size_t)j * DIM);

    float acc[MROWS];
#pragma unroll
    for (int r = 0; r < MROWS; ++r) acc[r] = 0.f;

    for (int kt = 0; kt < 4; ++kt) {
        // cooperative tile load: 2048 float4, 8 per thread, coalesced
#pragma unroll
        for (int i = tid; i < MROWS * 64; i += 256) {
            int r  = i >> 6;
            int c4 = i & 63;
            aS[i] = A4[r * K4 + kt * 64 + c4];
        }
        __syncthreads();

        fvec4 w = Wrow[kt * 64 + lane];        // coalesced across lanes
#pragma unroll
        for (int r = 0; r < MROWS; ++r) {
            fvec4 a = aS[r * 64 + lane];       // ds_read_b128, conflict-free
            acc[r] += w.x * a.x + w.y * a.y + w.z * a.z + w.w * a.w;
        }
        __syncthreads();
    }

    // reduce each row-accumulator across the 64 lanes
#pragma unroll
    for (int r = 0; r < MROWS; ++r) {
        float v = acc[r];
        for (int off = 32; off > 0; off >>= 1) v += __shfl_down(v, off, 64);
        acc[r] = v;
    }

    if (lane == 0) {
        const float b = bias[j];
#pragma unroll
        for (int r = 0; r < MROWS; ++r) C[r * DIM + j] = acc[r] + b;
    }
}

// out[(bt*TPF + p), :] = y[bt, :] for p in [0,TPF). grid = 32*SPLITS blocks.
__global__ __launch_bounds__(256) void bcast(const float* __restrict__ y,
                                             float* __restrict__ out) {
    const int bt = blockIdx.x / SPLITS;
    const int ch = blockIdx.x % SPLITS;

    const fvec4 val = ((const fvec4*)(y + (size_t)bt * DIM))[threadIdx.x];

    fvec4* o = (fvec4*)out + ((size_t)bt * TPF + (size_t)ch * CHUNK) * K4;
#pragma unroll
    for (int i = 0; i < CHUNK; ++i) {
        __builtin_nontemporal_store(val, &o[(size_t)i * K4 + threadIdx.x]);
    }
}

extern "C" void kernel_launch(void* const* d_in, const int* in_sizes, int n_in,
                              void* d_out, int out_size, void* d_ws, size_t ws_size,
                              hipStream_t stream) {
    // inputs: 0=x 1=c 2=Wq 3=bq 4=Wk 5=bk 6=Wv 7=bv 8=Wo 9=bo
    const float* c  = (const float*)d_in[1];
    const float* Wv = (const float*)d_in[6];
    const float* bv = (const float*)d_in[7];
    const float* Wo = (const float*)d_in[8];
    const float* bo = (const float*)d_in[9];
    float* out = (float*)d_out;

    float* v = (float*)d_ws;                  // [32,1024]
    float* y = (float*)d_ws + MROWS * DIM;    // [32,1024]

    gemm32<<<256, 256, 0, stream>>>(c, Wv, bv, v);
    gemm32<<<256, 256, 0, stream>>>(v, Wo, bo, y);
    bcast<<<MROWS * SPLITS, 256, 0, stream>>>(y, out);
}

// Round 3
// 330.338 us; speedup vs baseline: 1.0446x; 1.0446x over previous
//
#include <hip/hip_runtime.h>
#include <hip/hip_bf16.h>

// FrameWiseCrossAttention: kv_len==1 => softmax==1 => out = broadcast(y),
// y = (c @ Wv^T + bv) @ Wo^T + bo. x/Wq/Wk/bq/bk are mathematically unused.
// B=2, T=16, tpf=1560, N=24960, DIM=1024. M = B*T = 32 rows.

#define DIM    1024
#define K4     (DIM / 4)    // 256 float4 per row
#define MROWS  32           // B*T
#define TPF    1560
#define CHUNK  13
#define SPLITS 120          // 120 * 13 = 1560

typedef float fvec4 __attribute__((ext_vector_type(4)));

// C[32,1024] = A[32,1024] @ W[1024,1024]^T + bias.
// 512 blocks x 256 threads. Block b owns output columns j0=2b, 2b+1 (its 4
// waves share the two W rows -> L1 reuse). Wave w owns rows r0=8w..8w+7.
// K is lane-sliced: lane covers float4 indices {t*64 + lane, t=0..3} so every
// load instruction is a fully coalesced 1KB dwordx4. No LDS, no barriers.
__global__ __launch_bounds__(256) void gemm_thin(const float* __restrict__ A,
                                                 const float* __restrict__ W,
                                                 const float* __restrict__ bias,
                                                 float* __restrict__ C) {
    const int wave = threadIdx.x >> 6;
    const int lane = threadIdx.x & 63;
    const int j0   = blockIdx.x * 2;
    const int r0   = wave * 8;

    const fvec4* __restrict__ A4 = (const fvec4*)A;                       // row stride K4
    const fvec4* __restrict__ W0 = (const fvec4*)(W + (size_t)j0 * DIM);
    const fvec4* __restrict__ W1 = (const fvec4*)(W + (size_t)(j0 + 1) * DIM);

    fvec4 wa[4], wb[4];
#pragma unroll
    for (int t = 0; t < 4; ++t) {
        wa[t] = W0[t * 64 + lane];
        wb[t] = W1[t * 64 + lane];
    }

    float accA[8], accB[8];
#pragma unroll
    for (int r = 0; r < 8; ++r) { accA[r] = 0.f; accB[r] = 0.f; }

#pragma unroll
    for (int r = 0; r < 8; ++r) {
        const fvec4* __restrict__ Ar = A4 + (size_t)(r0 + r) * K4;
#pragma unroll
        for (int t = 0; t < 4; ++t) {
            fvec4 a = Ar[t * 64 + lane];
            accA[r] += a.x * wa[t].x + a.y * wa[t].y + a.z * wa[t].z + a.w * wa[t].w;
            accB[r] += a.x * wb[t].x + a.y * wb[t].y + a.z * wb[t].z + a.w * wb[t].w;
        }
    }

    // reduce across 64 lanes
#pragma unroll
    for (int r = 0; r < 8; ++r) {
        float va = accA[r], vb = accB[r];
#pragma unroll
        for (int off = 32; off > 0; off >>= 1) {
            va += __shfl_down(va, off, 64);
            vb += __shfl_down(vb, off, 64);
        }
        accA[r] = va; accB[r] = vb;
    }

    if (lane == 0) {
        const float b0 = bias[j0], b1 = bias[j0 + 1];
#pragma unroll
        for (int r = 0; r < 8; ++r) {
            C[(size_t)(r0 + r) * DIM + j0]     = accA[r] + b0;
            C[(size_t)(r0 + r) * DIM + j0 + 1] = accB[r] + b1;
        }
    }
}

// out[bt*TPF + p, :] = y[bt, :]. 3840 blocks x 256 threads, 13 rows each.
__global__ __launch_bounds__(256) void bcast(const float* __restrict__ y,
                                             float* __restrict__ out) {
    const int bt = blockIdx.x / SPLITS;
    const int ch = blockIdx.x % SPLITS;

    const fvec4 val = ((const fvec4*)(y + (size_t)bt * DIM))[threadIdx.x];

    fvec4* o = (fvec4*)out + ((size_t)bt * TPF + (size_t)ch * CHUNK) * K4;
#pragma unroll
    for (int i = 0; i < CHUNK; ++i) {
        o[(size_t)i * K4 + threadIdx.x] = val;
    }
}

extern "C" void kernel_launch(void* const* d_in, const int* in_sizes, int n_in,
                              void* d_out, int out_size, void* d_ws, size_t ws_size,
                              hipStream_t stream) {
    // inputs: 0=x 1=c 2=Wq 3=bq 4=Wk 5=bk 6=Wv 7=bv 8=Wo 9=bo
    const float* c  = (const float*)d_in[1];
    const float* Wv = (const float*)d_in[6];
    const float* bv = (const float*)d_in[7];
    const float* Wo = (const float*)d_in[8];
    const float* bo = (const float*)d_in[9];
    float* out = (float*)d_out;

    float* v = (float*)d_ws;                  // [32,1024]
    float* y = (float*)d_ws + MROWS * DIM;    // [32,1024]

    gemm_thin<<<DIM / 2, 256, 0, stream>>>(c, Wv, bv, v);
    gemm_thin<<<DIM / 2, 256, 0, stream>>>(v, Wo, bo, y);
    bcast<<<MROWS * SPLITS, 256, 0, stream>>>(y, out);
}